// Round 8
// baseline (850.784 us; speedup 1.0000x reference)
//
#include <hip/hip_runtime.h>
#include <hip/hip_fp16.h>
#include <math.h>

#define EPSBN 1e-5f
#define NBMAX 2048          // max buckets (256 rows each) for radix path
#define TPT 32              // entries per thread in passA
#define CAPB 8192           // passB LDS staging capacity (entries)

typedef int int4v __attribute__((ext_vector_type(4)));

__device__ __forceinline__ float elu1(float x) { return x > 0.f ? x : expm1f(x); }

// dot of 8 half pairs (packed in float4 bit patterns), fp32 accumulate
__device__ __forceinline__ float dot8h(float4 hv, float4 wv, float acc) {
#if defined(__has_builtin)
#if __has_builtin(__builtin_amdgcn_fdot2)
    typedef _Float16 h2v __attribute__((ext_vector_type(2)));
    union { float4 f; h2v h[4]; } a, b;
    a.f = hv; b.f = wv;
#pragma unroll
    for (int i = 0; i < 4; ++i)
        acc = __builtin_amdgcn_fdot2(a.h[i], b.h[i], acc, false);
    return acc;
#endif
#endif
    const __half2* ha = (const __half2*)&hv;
    const __half2* wa = (const __half2*)&wv;
#pragma unroll
    for (int i = 0; i < 4; ++i) {
        float2 hf = __half22float2(ha[i]);
        float2 wf = __half22float2(wa[i]);
        acc = fmaf(hf.x, wf.x, acc);
        acc = fmaf(hf.y, wf.y, acc);
    }
    return acc;
}

// ============================================================================
// CSR build part 1: per-row histogram + offsets
// ============================================================================

__global__ void hist_kernel(const int* __restrict__ out_idx, int* __restrict__ cnt, int M) {
    int m4 = blockIdx.x * blockDim.x + threadIdx.x;
    int m = m4 * 4;
    if (m >= M) return;
    size_t e = (size_t)blockIdx.y * M + m;
    if (m + 3 < M) {
        int4v v = __builtin_nontemporal_load((const int4v*)(out_idx + e));
        atomicAdd(&cnt[v.x], 1);
        atomicAdd(&cnt[v.y], 1);
        atomicAdd(&cnt[v.z], 1);
        atomicAdd(&cnt[v.w], 1);
    } else {
        for (int j = 0; j < M - m; ++j) atomicAdd(&cnt[out_idx[e + j]], 1);
    }
}

__global__ void scan_block_sums(const int* __restrict__ cnt, int* __restrict__ bsum, int N) {
    __shared__ int tmp[256];
    int i = blockIdx.x * 256 + threadIdx.x;
    tmp[threadIdx.x] = (i < N) ? cnt[i] : 0;
    __syncthreads();
    for (int off = 128; off > 0; off >>= 1) {
        if (threadIdx.x < off) tmp[threadIdx.x] += tmp[threadIdx.x + off];
        __syncthreads();
    }
    if (threadIdx.x == 0) bsum[blockIdx.x] = tmp[0];
}

__global__ void scan_bsums(int* __restrict__ bsum, int nb, int* __restrict__ offsets, int N, int E) {
    __shared__ int tmp[256];
    int carry = 0;
    for (int base = 0; base < nb; base += 256) {
        int i = base + threadIdx.x;
        int v = (i < nb) ? bsum[i] : 0;
        tmp[threadIdx.x] = v;
        __syncthreads();
        for (int off = 1; off < 256; off <<= 1) {
            int t = (threadIdx.x >= off) ? tmp[threadIdx.x - off] : 0;
            __syncthreads();
            tmp[threadIdx.x] += t;
            __syncthreads();
        }
        int incl = tmp[threadIdx.x];
        int total = tmp[255];
        if (i < nb) bsum[i] = incl - v + carry;   // exclusive
        carry += total;
        __syncthreads();
    }
    if (threadIdx.x == 0) offsets[N] = E;
}

__global__ void scan_final(const int* __restrict__ cnt, const int* __restrict__ bsum,
                           int* __restrict__ offsets, int* __restrict__ cursor, int N) {
    __shared__ int tmp[256];
    int i = blockIdx.x * 256 + threadIdx.x;
    int v = (i < N) ? cnt[i] : 0;
    tmp[threadIdx.x] = v;
    __syncthreads();
    for (int off = 1; off < 256; off <<= 1) {
        int t = (threadIdx.x >= off) ? tmp[threadIdx.x - off] : 0;
        __syncthreads();
        tmp[threadIdx.x] += t;
        __syncthreads();
    }
    if (i < N) {
        int o = tmp[threadIdx.x] - v + bsum[blockIdx.x];
        offsets[i] = o;
        cursor[i] = o;
    }
}

// ============================================================================
// CSR build part 2a (radix path): bucket scatter. bucket = out >> 8.
// ============================================================================

__global__ void init_bcursor(const int* __restrict__ offsets, int* __restrict__ bcur, int NB, int N) {
    int b = blockIdx.x * 256 + threadIdx.x;
    if (b >= NB) return;
    int row = b << 8; if (row > N) row = N;
    bcur[b * 16] = offsets[row];
}

__global__ void passA(const int* __restrict__ in_idx, const int* __restrict__ out_idx,
                      int* __restrict__ bcur, unsigned* __restrict__ tmp, int M, int NB) {
    __shared__ int cnt[NBMAX];
    __shared__ int gbase[NBMAX];
    for (int t = threadIdx.x; t < NB; t += 256) cnt[t] = 0;
    __syncthreads();
    int k = blockIdx.y;
    int base = blockIdx.x * (256 * TPT);
    unsigned pk[TPT];
    int bk[TPT];
#pragma unroll
    for (int j = 0; j < TPT; ++j) {
        int m = base + threadIdx.x + j * 256;
        if (m < M) {
            size_t e = (size_t)k * M + m;
            unsigned in = (unsigned)__builtin_nontemporal_load(in_idx + e);
            unsigned out = (unsigned)__builtin_nontemporal_load(out_idx + e);
            pk[j] = ((out & 255u) << 24) | ((unsigned)k << 19) | in;
            bk[j] = (int)(out >> 8);
            atomicAdd(&cnt[bk[j]], 1);
        } else bk[j] = -1;
    }
    __syncthreads();
    for (int b = threadIdx.x; b < NB; b += 256) {
        int c = cnt[b];
        gbase[b] = c ? atomicAdd(&bcur[b * 16], c) : 0;
        cnt[b] = 0;   // reuse as local slot cursor
    }
    __syncthreads();
#pragma unroll
    for (int j = 0; j < TPT; ++j) {
        if (bk[j] >= 0) {
            int slot = atomicAdd(&cnt[bk[j]], 1);
            tmp[gbase[bk[j]] + slot] = pk[j];
        }
    }
}

// Pass B: one block per bucket; counting-sort bucket into LDS, coalesced write.
__global__ void passB(const unsigned* __restrict__ tmp, const int* __restrict__ offsets,
                      unsigned* __restrict__ entries, int N) {
    __shared__ int cur[256];
    __shared__ unsigned stg[CAPB];
    int b = blockIdx.x;
    int r0 = b << 8;
    int rend = r0 + 256; if (rend > N) rend = N;
    int nr = rend - r0;
    int gbeg = offsets[r0];
    int gend = offsets[rend];
    int count = gend - gbeg;
    if (threadIdx.x < nr) cur[threadIdx.x] = offsets[r0 + threadIdx.x] - gbeg;
    __syncthreads();
    if (count <= CAPB) {
        for (int i = threadIdx.x; i < count; i += 256) {
            unsigned v = __builtin_nontemporal_load(tmp + gbeg + i);
            int slot = atomicAdd(&cur[v >> 24], 1);
            stg[slot] = v & 0x00FFFFFFu;
        }
        __syncthreads();
        for (int i = threadIdx.x; i < count; i += 256)
            entries[gbeg + i] = stg[i];
    } else {
        for (int i = threadIdx.x; i < count; i += 256) {
            unsigned v = __builtin_nontemporal_load(tmp + gbeg + i);
            int slot = atomicAdd(&cur[v >> 24], 1);
            entries[gbeg + slot] = v & 0x00FFFFFFu;
        }
    }
}

// ============================================================================
// CSR build part 2b (fallback): direct atomic scatter
// ============================================================================

__global__ void scatter_entries(const int* __restrict__ in_idx, const int* __restrict__ out_idx,
                                int* __restrict__ cursor, unsigned* __restrict__ entries, int M, int shift) {
    int m = blockIdx.x * blockDim.x + threadIdx.x;
    if (m >= M) return;
    int k = blockIdx.y;
    size_t e = (size_t)k * M + m;
    int pos = atomicAdd(&cursor[out_idx[e]], 1);
    entries[pos] = (unsigned)in_idx[e] | ((unsigned)k << shift);
}

// W2T[k][d][c] = (half)W2[k][c][d]  (27 KB, L1-resident)
__global__ void transpose_W2(const float* __restrict__ W2, __half* __restrict__ W2T, int total) {
    int i = blockIdx.x * 256 + threadIdx.x;
    if (i >= total) return;
    int k = i >> 9;
    int r = i & 511;
    int c = r >> 5, d = r & 31;
    W2T[(k << 9) | (d << 4) | c] = __float2half(W2[i]);
}

// ============================================================================
// Stage 1 gather: 16 threads per row, broadcast entry loads, fp16 h out
// ============================================================================

__global__ void s1_gather_f16(const float* __restrict__ x, const float* __restrict__ W1,
                              const float* __restrict__ g1, const float* __restrict__ b1,
                              const float* __restrict__ m1, const float* __restrict__ v1,
                              const int* __restrict__ offsets, const unsigned* __restrict__ entries,
                              __half* __restrict__ h, int N, int shift, unsigned mask) {
    int row = blockIdx.x * 16 + (threadIdx.x >> 4);
    int c = threadIdx.x & 15;
    if (row >= N) return;
    int beg = offsets[row], end = offsets[row + 1];
    float acc = 0.f;
    for (int base = beg; base < end; base += 16) {
        int cnt = end - base; if (cnt > 16) cnt = 16;
        unsigned ev = __builtin_nontemporal_load(entries + base + (c < cnt ? c : cnt - 1));
        int j = 0;
        for (; j + 1 < cnt; j += 2) {
            unsigned pk0 = __shfl(ev, j, 16);
            unsigned pk1 = __shfl(ev, j + 1, 16);
            float x0 = x[pk0 & mask];
            float x1 = x[pk1 & mask];
            acc = fmaf(x0, W1[(pk0 >> shift) * 16 + c], acc);
            acc = fmaf(x1, W1[(pk1 >> shift) * 16 + c], acc);
        }
        if (j < cnt) {
            unsigned pk0 = __shfl(ev, j, 16);
            acc = fmaf(x[pk0 & mask], W1[(pk0 >> shift) * 16 + c], acc);
        }
    }
    float scale = g1[c] * rsqrtf(v1[c] + EPSBN);
    float bias = b1[c] - m1[c] * scale;
    h[(size_t)row * 16 + c] = __float2half(elu1(acc * scale + bias));
}

// ============================================================================
// Stage 2 gather: 32 threads per row, 4-entry unroll, 4 accumulators,
// fdot2 dots, nt streaming for entries/out. h reads stay cached.
// ============================================================================

__global__ void s2_gather_f16(const __half* __restrict__ h, const __half* __restrict__ W2T,
                              const float* __restrict__ g2, const float* __restrict__ b2,
                              const float* __restrict__ m2, const float* __restrict__ v2,
                              const int* __restrict__ offsets, const unsigned* __restrict__ entries,
                              float* __restrict__ out, int N, int shift, unsigned mask) {
    int row = blockIdx.x * 8 + (threadIdx.x >> 5);
    int d = threadIdx.x & 31;
    if (row >= N) return;
    int beg = offsets[row], end = offsets[row + 1];
    float acc0 = 0.f, acc1 = 0.f, acc2 = 0.f, acc3 = 0.f;
    for (int base = beg; base < end; base += 32) {
        int cnt = end - base; if (cnt > 32) cnt = 32;
        unsigned ev = __builtin_nontemporal_load(entries + base + (d < cnt ? d : cnt - 1));
        int j = 0;
        for (; j + 3 < cnt; j += 4) {
            unsigned pk0 = __shfl(ev, j, 32);
            unsigned pk1 = __shfl(ev, j + 1, 32);
            unsigned pk2 = __shfl(ev, j + 2, 32);
            unsigned pk3 = __shfl(ev, j + 3, 32);
            const float4* hp0 = (const float4*)(h + ((size_t)(pk0 & mask) << 4));
            const float4* hp1 = (const float4*)(h + ((size_t)(pk1 & mask) << 4));
            const float4* hp2 = (const float4*)(h + ((size_t)(pk2 & mask) << 4));
            const float4* hp3 = (const float4*)(h + ((size_t)(pk3 & mask) << 4));
            float4 ha0 = hp0[0], hb0 = hp0[1];
            float4 ha1 = hp1[0], hb1 = hp1[1];
            float4 ha2 = hp2[0], hb2 = hp2[1];
            float4 ha3 = hp3[0], hb3 = hp3[1];
            const float4* wp0 = (const float4*)(W2T + (((size_t)(pk0 >> shift) << 9) | ((unsigned)d << 4)));
            const float4* wp1 = (const float4*)(W2T + (((size_t)(pk1 >> shift) << 9) | ((unsigned)d << 4)));
            const float4* wp2 = (const float4*)(W2T + (((size_t)(pk2 >> shift) << 9) | ((unsigned)d << 4)));
            const float4* wp3 = (const float4*)(W2T + (((size_t)(pk3 >> shift) << 9) | ((unsigned)d << 4)));
            acc0 = dot8h(ha0, wp0[0], acc0);
            acc1 = dot8h(ha1, wp1[0], acc1);
            acc2 = dot8h(ha2, wp2[0], acc2);
            acc3 = dot8h(ha3, wp3[0], acc3);
            acc0 = dot8h(hb0, wp0[1], acc0);
            acc1 = dot8h(hb1, wp1[1], acc1);
            acc2 = dot8h(hb2, wp2[1], acc2);
            acc3 = dot8h(hb3, wp3[1], acc3);
        }
        for (; j < cnt; ++j) {
            unsigned pk0 = __shfl(ev, j, 32);
            const float4* hp0 = (const float4*)(h + ((size_t)(pk0 & mask) << 4));
            float4 ha0 = hp0[0], hb0 = hp0[1];
            const float4* wp0 = (const float4*)(W2T + (((size_t)(pk0 >> shift) << 9) | ((unsigned)d << 4)));
            acc0 = dot8h(ha0, wp0[0], acc0);
            acc0 = dot8h(hb0, wp0[1], acc0);
        }
    }
    float acc = (acc0 + acc1) + (acc2 + acc3);
    float scale = g2[d] * rsqrtf(v2[d] + EPSBN);
    float bias = b2[d] - m2[d] * scale;
    __builtin_nontemporal_store(elu1(acc * scale + bias), out + (size_t)row * 32 + d);
}

// ============================================================================
// Last-resort fallback: atomic path (fp32 throughout)
// ============================================================================

__global__ void s1_scatter_slab(const float* __restrict__ x, const int* __restrict__ in_idx,
                                const int* __restrict__ out_idx, float* __restrict__ s, int M, int N) {
    int m = blockIdx.x * blockDim.x + threadIdx.x;
    if (m >= M) return;
    int k = blockIdx.y;
    size_t e = (size_t)k * M + m;
    unsafeAtomicAdd(&s[(size_t)k * N + out_idx[e]], x[in_idx[e]]);
}

__global__ void s1_combine(const float* __restrict__ s, const float* __restrict__ W1,
                           const float* __restrict__ g1, const float* __restrict__ b1,
                           const float* __restrict__ m1, const float* __restrict__ v1,
                           float* __restrict__ h, int N, int K) {
    __shared__ float w[32 * 16];
    __shared__ float sc[16], bi[16];
    for (int t = threadIdx.x; t < K * 16; t += blockDim.x) w[t] = W1[t];
    if (threadIdx.x < 16) {
        float scale = g1[threadIdx.x] * rsqrtf(v1[threadIdx.x] + EPSBN);
        sc[threadIdx.x] = scale;
        bi[threadIdx.x] = b1[threadIdx.x] - m1[threadIdx.x] * scale;
    }
    __syncthreads();
    int n = blockIdx.x * blockDim.x + threadIdx.x;
    if (n >= N) return;
    float acc[16];
#pragma unroll
    for (int c = 0; c < 16; ++c) acc[c] = 0.f;
    for (int k = 0; k < K; ++k) {
        float sv = s[(size_t)k * N + n];
#pragma unroll
        for (int c = 0; c < 16; ++c) acc[c] = fmaf(sv, w[k * 16 + c], acc[c]);
    }
    float4* hv = (float4*)(h + (size_t)n * 16);
#pragma unroll
    for (int q = 0; q < 4; ++q) {
        float4 o;
        o.x = elu1(acc[q * 4 + 0] * sc[q * 4 + 0] + bi[q * 4 + 0]);
        o.y = elu1(acc[q * 4 + 1] * sc[q * 4 + 1] + bi[q * 4 + 1]);
        o.z = elu1(acc[q * 4 + 2] * sc[q * 4 + 2] + bi[q * 4 + 2]);
        o.w = elu1(acc[q * 4 + 3] * sc[q * 4 + 3] + bi[q * 4 + 3]);
        hv[q] = o;
    }
}

__global__ void bn_elu_c(float* __restrict__ buf, const float* __restrict__ g,
                         const float* __restrict__ b, const float* __restrict__ m,
                         const float* __restrict__ v, size_t total, int cmask) {
    size_t i = (size_t)blockIdx.x * blockDim.x + threadIdx.x;
    if (i >= total) return;
    int c = (int)(i & (size_t)cmask);
    float scale = g[c] * rsqrtf(v[c] + EPSBN);
    buf[i] = elu1((buf[i] - m[c]) * scale + b[c]);
}

__global__ void s2_scatter(const float* __restrict__ h, const float* __restrict__ W2,
                           const int* __restrict__ in_idx, const int* __restrict__ out_idx,
                           float* __restrict__ acc, int M) {
    __shared__ float w[16 * 32];
    int k = blockIdx.y;
    for (int t = threadIdx.x; t < 512; t += blockDim.x) w[t] = W2[(size_t)k * 512 + t];
    __syncthreads();
    int m = blockIdx.x * blockDim.x + threadIdx.x;
    if (m >= M) return;
    size_t e = (size_t)k * M + m;
    int in = in_idx[e], out = out_idx[e];
    const float4* hr = (const float4*)(h + (size_t)in * 16);
    float4 h0 = hr[0], h1 = hr[1], h2 = hr[2], h3 = hr[3];
    float hrow[16] = {h0.x, h0.y, h0.z, h0.w, h1.x, h1.y, h1.z, h1.w,
                      h2.x, h2.y, h2.z, h2.w, h3.x, h3.y, h3.z, h3.w};
    float yv[32];
#pragma unroll
    for (int dd = 0; dd < 32; ++dd) yv[dd] = 0.f;
#pragma unroll
    for (int c = 0; c < 16; ++c) {
        float hv = hrow[c];
#pragma unroll
        for (int dd = 0; dd < 32; ++dd) yv[dd] = fmaf(hv, w[c * 32 + dd], yv[dd]);
    }
    float* ar = acc + (size_t)out * 32;
#pragma unroll
    for (int dd = 0; dd < 32; ++dd) unsafeAtomicAdd(&ar[dd], yv[dd]);
}

// ============================================================================

extern "C" void kernel_launch(void* const* d_in, const int* in_sizes, int n_in,
                              void* d_out, int out_size, void* d_ws, size_t ws_size,
                              hipStream_t stream) {
    const float* x  = (const float*)d_in[0];
    const float* W1 = (const float*)d_in[1];
    const float* g1 = (const float*)d_in[2];
    const float* b1 = (const float*)d_in[3];
    const float* m1 = (const float*)d_in[4];
    const float* v1 = (const float*)d_in[5];
    const float* W2 = (const float*)d_in[6];
    const float* g2 = (const float*)d_in[7];
    const float* b2 = (const float*)d_in[8];
    const float* m2 = (const float*)d_in[9];
    const float* v2 = (const float*)d_in[10];
    const int* in_idx  = (const int*)d_in[11];
    const int* out_idx = (const int*)d_in[12];

    const int N  = in_sizes[0];
    const int C1 = in_sizes[2];           // 16
    const int K  = in_sizes[1] / C1;      // 27
    const int M  = in_sizes[11] / K;      // 200000
    const int E  = K * M;                 // 5.4M
    const int nb = (N + 255) / 256;
    const int NB = (N + 255) >> 8;        // radix buckets (256 rows each)

    float* out = (float*)d_out;
    dim3 blk(256);
    dim3 grdKM((M + 255) / 256, K);

    auto align256 = [](size_t v) { return (v + 255) & ~(size_t)255; };
    size_t cntB   = align256((size_t)N * 4);
    size_t offB   = align256((size_t)(N + 1) * 4);
    size_t bsumB  = align256((size_t)nb * 4);
    size_t entB   = align256((size_t)E * 4);
    size_t w2tB   = align256((size_t)K * 512 * 2);
    size_t hB     = align256((size_t)N * 16 * 2);
    size_t baseNeed = cntB + offB + bsumB + entB + w2tB + hB;

    size_t bcurB  = align256((size_t)NB * 16 * 4);
    size_t tmpB   = align256((size_t)E * 4);
    size_t curB   = align256((size_t)N * 4);

    bool canCSR   = (N < (1 << 24)) && (K < 256);
    bool canRadix = (N <= (1 << 19)) && (K <= 32) && (NB <= NBMAX) &&
                    (ws_size >= baseNeed + bcurB + tmpB + curB);

    if (canCSR && ws_size >= baseNeed + curB) {
        char* p = (char*)d_ws;
        int* cnt        = (int*)p;            p += cntB;
        int* offsets    = (int*)p;            p += offB;
        int* bsum       = (int*)p;            p += bsumB;
        unsigned* ent   = (unsigned*)p;       p += entB;
        __half* W2T     = (__half*)p;         p += w2tB;
        __half* h       = (__half*)p;         p += hB;
        int* cursor     = (int*)p;            p += curB;

        const int shift = canRadix ? 19 : 24;
        const unsigned mask = canRadix ? 0x7FFFFu : 0xFFFFFFu;

        hipMemsetAsync(cnt, 0, (size_t)N * 4, stream);
        hist_kernel<<<dim3((M / 4 + 256) / 256, K), blk, 0, stream>>>(out_idx, cnt, M);
        transpose_W2<<<dim3((K * 512 + 255) / 256), blk, 0, stream>>>(W2, W2T, K * 512);
        scan_block_sums<<<dim3(nb), blk, 0, stream>>>(cnt, bsum, N);
        scan_bsums<<<dim3(1), blk, 0, stream>>>(bsum, nb, offsets, N, E);
        scan_final<<<dim3(nb), blk, 0, stream>>>(cnt, bsum, offsets, cursor, N);

        if (canRadix) {
            int* bcur     = (int*)p;          p += bcurB;
            unsigned* tmp = (unsigned*)p;
            init_bcursor<<<dim3((NB + 255) / 256), blk, 0, stream>>>(offsets, bcur, NB, N);
            passA<<<dim3((M + 256 * TPT - 1) / (256 * TPT), K), blk, 0, stream>>>(in_idx, out_idx, bcur, tmp, M, NB);
            passB<<<dim3(NB), blk, 0, stream>>>(tmp, offsets, ent, N);
        } else {
            scatter_entries<<<grdKM, blk, 0, stream>>>(in_idx, out_idx, cursor, ent, M, shift);
        }

        s1_gather_f16<<<dim3((N + 15) / 16), blk, 0, stream>>>(x, W1, g1, b1, m1, v1, offsets, ent, h, N, shift, mask);
        s2_gather_f16<<<dim3((N + 7) / 8), blk, 0, stream>>>(h, W2T, g2, b2, m2, v2, offsets, ent, out, N, shift, mask);
        return;
    }

    // ---------------- fallback: atomic path ----------------
    size_t sBytes = align256((size_t)K * N * 4);
    size_t hBytes = (size_t)N * 16 * 4;
    float* hf = (float*)d_ws;
    if (ws_size >= sBytes + hBytes) {
        float* s = (float*)d_ws;
        hf = (float*)((char*)d_ws + sBytes);
        hipMemsetAsync(s, 0, (size_t)K * N * 4, stream);
        s1_scatter_slab<<<grdKM, blk, 0, stream>>>(x, in_idx, out_idx, s, M, N);
        s1_combine<<<dim3((N + 255) / 256), blk, 0, stream>>>(s, W1, g1, b1, m1, v1, hf, N, K);
    }
    hipMemsetAsync(out, 0, (size_t)N * 32 * 4, stream);
    s2_scatter<<<grdKM, blk, 0, stream>>>(hf, W2, in_idx, out_idx, out, M);
    size_t tot2 = (size_t)N * 32;
    bn_elu_c<<<dim3((unsigned)((tot2 + 255) / 256)), blk, 0, stream>>>(out, g2, b2, m2, v2, tot2, 31);
}